// Round 2
// baseline (1457.834 us; speedup 1.0000x reference)
//
#include <hip/hip_runtime.h>
#include <math.h>

#define C 1536
#define D2 3072
#define L 1024
#define KC 64      // k-chunk per staging pass (16 float4 quads)
#define NB 512     // persistent grid: 2 blocks/CU on 256 CUs
#define NT 256
#define CH 16      // flash L-chunks: 16 chunks x 32 b = 512 blocks
#define LPW 16     // l's per wave = L/(CH*4)

__device__ inline float dot4(float4 a, float4 b) {
    return a.x * b.x + a.y * b.y + a.z * b.z + a.w * b.w;
}
__device__ inline float4 ld4(const float* p) { return *(const float4*)p; }
__device__ inline void   st4(float* p, float4 v) { *(float4*)p = v; }

// swizzled LDS quad address (float index): row*KC + (q ^ ((row>>2)&7))*4
__device__ inline int sw(int row, int q) {
    return row * KC + ((q ^ ((row >> 2) & 7)) << 2);
}

struct Params {
    const float *x, *lfb, *theta_w, *theta_b, *phi_w, *gi_w, *gi_b;
    const float *ln_g, *ln_b, *fc_w, *fc_b, *fcn_w, *fcn_b;
    const float *w1, *b1, *w2, *b2, *w3, *b3, *wt, *bt;
    float *out;
    float *part, *partH, *pv, *pm, *ps, *theta, *u, *vbuf, *oln, *lt;
    unsigned *bar;   // 16 x u32, memset to 0 before launch (single-use counters)
};

// ---- software grid barrier: single-use counter per idx ----
// Co-residency of all NB blocks is guaranteed: __launch_bounds__(256,2) caps
// VGPR at 256 and LDS is 24KB -> 2 blocks/CU schedulable, NB = 2*256.
__device__ inline void gridbar(unsigned* bar, int idx) {
    __syncthreads();
    if (threadIdx.x == 0) {
        __threadfence();   // agent-scope release of this block's prior writes
        __hip_atomic_fetch_add(&bar[idx], 1u, __ATOMIC_ACQ_REL, __HIP_MEMORY_SCOPE_AGENT);
        int spins = 0;
        while (__hip_atomic_load(&bar[idx], __ATOMIC_ACQUIRE, __HIP_MEMORY_SCOPE_AGENT) < NB) {
            __builtin_amdgcn_s_sleep(4);
            if (++spins > (1 << 20)) break;   // ~100ms bail-out: fail loud, not hang
        }
        __threadfence();   // acquire side for the rest of the block
    }
    __syncthreads();
}

// ---- split-K GEMM partial tile: A(32xK rm) @ W(NxK rm).T, one (jt,kb) tile ----
__device__ void gemm_nn(const float* __restrict__ A, const float* __restrict__ W,
                        float* __restrict__ part, int N, int K, int kchunks,
                        int jt, int kb, float* xs, float* wsm) {
    int tid = threadIdx.x;
    int j0 = jt * 64;
    int tb = tid & 15, tj = tid >> 4;
    float4 acc0 = make_float4(0.f, 0.f, 0.f, 0.f);
    float4 acc1 = make_float4(0.f, 0.f, 0.f, 0.f);
    for (int c = 0; c < kchunks; ++c) {
        int k0 = (kb * kchunks + c) * KC;
        __syncthreads();
        #pragma unroll
        for (int p = 0; p < 2; ++p) {
            int f = tid + 256 * p, row = f >> 4, q = f & 15;
            st4(xs + sw(row, q), ld4(A + (size_t)row * K + k0 + 4 * q));
        }
        #pragma unroll
        for (int p = 0; p < 4; ++p) {
            int f = tid + 256 * p, row = f >> 4, q = f & 15;
            st4(wsm + sw(row, q), ld4(W + (size_t)(j0 + row) * K + k0 + 4 * q));
        }
        __syncthreads();
        #pragma unroll
        for (int kq = 0; kq < 16; ++kq) {
            float4 x0 = ld4(xs + sw(2 * tb, kq));
            float4 x1 = ld4(xs + sw(2 * tb + 1, kq));
            float4 w0 = ld4(wsm + sw(4 * tj + 0, kq));
            float4 w1 = ld4(wsm + sw(4 * tj + 1, kq));
            float4 w2 = ld4(wsm + sw(4 * tj + 2, kq));
            float4 w3 = ld4(wsm + sw(4 * tj + 3, kq));
            acc0.x += dot4(x0, w0); acc0.y += dot4(x0, w1);
            acc0.z += dot4(x0, w2); acc0.w += dot4(x0, w3);
            acc1.x += dot4(x1, w0); acc1.y += dot4(x1, w1);
            acc1.z += dot4(x1, w2); acc1.w += dot4(x1, w3);
        }
    }
    st4(part + ((size_t)kb * 32 + 2 * tb + 0) * N + j0 + 4 * tj, acc0);
    st4(part + ((size_t)kb * 32 + 2 * tb + 1) * N + j0 + 4 * tj, acc1);
}

// ---- same, W stored k-major (KxN rm): transpose W tile through LDS ----
__device__ void gemm_nt(const float* __restrict__ A, const float* __restrict__ W,
                        float* __restrict__ part, int N, int K, int kchunks,
                        int jt, int kb, float* xs, float* wsm) {
    int tid = threadIdx.x;
    int j0 = jt * 64;
    int tb = tid & 15, tj = tid >> 4;
    float4 acc0 = make_float4(0.f, 0.f, 0.f, 0.f);
    float4 acc1 = make_float4(0.f, 0.f, 0.f, 0.f);
    for (int c = 0; c < kchunks; ++c) {
        int k0 = (kb * kchunks + c) * KC;
        __syncthreads();
        #pragma unroll
        for (int p = 0; p < 2; ++p) {
            int f = tid + 256 * p, row = f >> 4, q = f & 15;
            st4(xs + sw(row, q), ld4(A + (size_t)row * K + k0 + 4 * q));
        }
        #pragma unroll
        for (int p = 0; p < 4; ++p) {
            int f = tid + 256 * p;
            int r = f >> 4;          // k-row within tile
            int cq = f & 15;         // j-quad
            float4 v = ld4(W + (size_t)(k0 + r) * N + j0 + 4 * cq);
            wsm[sw(4 * cq + 0, r >> 2) + (r & 3)] = v.x;
            wsm[sw(4 * cq + 1, r >> 2) + (r & 3)] = v.y;
            wsm[sw(4 * cq + 2, r >> 2) + (r & 3)] = v.z;
            wsm[sw(4 * cq + 3, r >> 2) + (r & 3)] = v.w;
        }
        __syncthreads();
        #pragma unroll
        for (int kq = 0; kq < 16; ++kq) {
            float4 x0 = ld4(xs + sw(2 * tb, kq));
            float4 x1 = ld4(xs + sw(2 * tb + 1, kq));
            float4 w0 = ld4(wsm + sw(4 * tj + 0, kq));
            float4 w1 = ld4(wsm + sw(4 * tj + 1, kq));
            float4 w2 = ld4(wsm + sw(4 * tj + 2, kq));
            float4 w3 = ld4(wsm + sw(4 * tj + 3, kq));
            acc0.x += dot4(x0, w0); acc0.y += dot4(x0, w1);
            acc0.z += dot4(x0, w2); acc0.w += dot4(x0, w3);
            acc1.x += dot4(x1, w0); acc1.y += dot4(x1, w1);
            acc1.z += dot4(x1, w2); acc1.w += dot4(x1, w3);
        }
    }
    st4(part + ((size_t)kb * 32 + 2 * tb + 0) * N + j0 + 4 * tj, acc0);
    st4(part + ((size_t)kb * 32 + 2 * tb + 1) * N + j0 + 4 * tj, acc1);
}

// ---- fcn GEMM partial tile: A synthesized = [x | lt], W = D2 x D2 rm ----
__device__ void gemm_feats(const float* __restrict__ x, const float* __restrict__ lt,
                           const float* __restrict__ W, float* __restrict__ part,
                           int jt, int kb, float* xs, float* wsm) {
    int tid = threadIdx.x;
    int j0 = jt * 64;
    int tb = tid & 15, tj = tid >> 4;
    float4 acc0 = make_float4(0.f, 0.f, 0.f, 0.f);
    float4 acc1 = make_float4(0.f, 0.f, 0.f, 0.f);
    for (int c = 0; c < 4; ++c) {
        int k0 = (kb * 4 + c) * KC;
        __syncthreads();
        #pragma unroll
        for (int p = 0; p < 2; ++p) {
            int f = tid + 256 * p, row = f >> 4, q = f & 15;
            int kk = k0 + 4 * q;
            float4 v = (kk < C) ? ld4(x + (size_t)row * C + kk)
                                : ld4(lt + (size_t)row * C + kk - C);
            st4(xs + sw(row, q), v);
        }
        #pragma unroll
        for (int p = 0; p < 4; ++p) {
            int f = tid + 256 * p, row = f >> 4, q = f & 15;
            st4(wsm + sw(row, q), ld4(W + (size_t)(j0 + row) * D2 + k0 + 4 * q));
        }
        __syncthreads();
        #pragma unroll
        for (int kq = 0; kq < 16; ++kq) {
            float4 x0 = ld4(xs + sw(2 * tb, kq));
            float4 x1 = ld4(xs + sw(2 * tb + 1, kq));
            float4 w0 = ld4(wsm + sw(4 * tj + 0, kq));
            float4 w1 = ld4(wsm + sw(4 * tj + 1, kq));
            float4 w2 = ld4(wsm + sw(4 * tj + 2, kq));
            float4 w3 = ld4(wsm + sw(4 * tj + 3, kq));
            acc0.x += dot4(x0, w0); acc0.y += dot4(x0, w1);
            acc0.z += dot4(x0, w2); acc0.w += dot4(x0, w3);
            acc1.x += dot4(x1, w0); acc1.y += dot4(x1, w1);
            acc1.z += dot4(x1, w2); acc1.w += dot4(x1, w3);
        }
    }
    st4(part + ((size_t)kb * 32 + 2 * tb + 0) * D2 + j0 + 4 * tj, acc0);
    st4(part + ((size_t)kb * 32 + 2 * tb + 1) * D2 + j0 + 4 * tj, acc1);
}

// ---- elementwise 12-way split-K reduce (+bias, +addx) over 32 x C ----
__device__ inline void reduce12(const float* __restrict__ part, const float* __restrict__ bias,
                                const float* __restrict__ addx, float* __restrict__ outp) {
    int i = blockIdx.x * NT + threadIdx.x;
    if (i < 32 * C) {
        int b = i / C, j = i - b * C;
        float s = 0.f;
        #pragma unroll
        for (int kk = 0; kk < 12; ++kk) s += part[((size_t)kk * 32 + b) * C + j];
        if (bias) s += bias[j];
        if (addx) s += addx[i];
        outp[i] = s;
    }
}

// ---- flash stage: scores + online softmax + weighted lfb accumulation ----
__device__ void flash_stage(const Params& p) {
    int gid = blockIdx.x;
    int b = gid & 31, chunk = gid >> 5;
    int wave = threadIdx.x >> 6, lane = threadIdx.x & 63;
    int widx = chunk * 4 + wave;

    const float scale = 39.19183588453085f;  // sqrt(1536)

    float uu[24];
    const float* ub = p.u + (size_t)b * C;
    #pragma unroll
    for (int t = 0; t < 6; ++t)
        *(float4*)(uu + 4 * t) = ld4(ub + 4 * lane + 256 * t);

    float m = -INFINITY, s = 0.f;
    float vv[24];
    #pragma unroll
    for (int t = 0; t < 24; ++t) vv[t] = 0.f;

    int l0 = chunk * (L / CH) + wave;
    for (int i = 0; i < LPW; ++i) {
        int l = l0 + i * 4;
        const float* row = p.lfb + ((size_t)b * L + l) * C;
        float xx[24];
        #pragma unroll
        for (int t = 0; t < 6; ++t)
            *(float4*)(xx + 4 * t) = ld4(row + 4 * lane + 256 * t);
        float d = 0.f;
        #pragma unroll
        for (int t = 0; t < 24; ++t) d += xx[t] * uu[t];
        #pragma unroll
        for (int off = 32; off > 0; off >>= 1) d += __shfl_xor(d, off, 64);
        float score = d * scale;
        float mn = fmaxf(m, score);
        float alpha = __expf(m - mn);
        float pr = __expf(score - mn);
        s = s * alpha + pr;
        #pragma unroll
        for (int t = 0; t < 24; ++t) vv[t] = vv[t] * alpha + pr * xx[t];
        m = mn;
    }

    if (lane == 0) { p.pm[b * 64 + widx] = m; p.ps[b * 64 + widx] = s; }
    float* pvb = p.pv + ((size_t)b * 64 + widx) * C;
    #pragma unroll
    for (int t = 0; t < 6; ++t)
        st4(pvb + 4 * lane + 256 * t, *(float4*)(vv + 4 * t));
}

// ---- combine wave-partials -> vbuf[b][c] (blocks 0..191) ----
__device__ void combine_stage(const Params& p, float* coef) {
    int gid = blockIdx.x;
    int b = gid & 31, cc = gid >> 5;
    int tid = threadIdx.x;
    if (tid < 64) {
        float mj = p.pm[b * 64 + tid];
        float M = mj;
        #pragma unroll
        for (int off = 32; off > 0; off >>= 1) M = fmaxf(M, __shfl_xor(M, off, 64));
        float ej = expf(mj - M);
        float S = p.ps[b * 64 + tid] * ej;
        #pragma unroll
        for (int off = 32; off > 0; off >>= 1) S += __shfl_xor(S, off, 64);
        coef[tid] = ej / S;
    }
    __syncthreads();
    int c = cc * 256 + tid;
    float acc = 0.f;
    #pragma unroll 8
    for (int j = 0; j < 64; ++j)
        acc += coef[j] * p.pv[((size_t)b * 64 + j) * C + c];
    p.vbuf[(size_t)b * C + c] = acc;
}

// ---- split-K reduce + gi_b + layernorm + relu (blocks 0..31) ----
__device__ void ln_stage(const Params& p, float* r1, float* r2) {
    int b = blockIdx.x, tid = threadIdx.x;
    float lv[6];
    float s1 = 0.f, s2 = 0.f;
    #pragma unroll
    for (int t = 0; t < 6; ++t) {
        int c = tid + 256 * t;
        float acc = 0.f;
        #pragma unroll
        for (int kk = 0; kk < 12; ++kk) acc += p.part[((size_t)kk * 32 + b) * C + c];
        acc += p.gi_b[c];
        lv[t] = acc; s1 += acc; s2 += acc * acc;
    }
    #pragma unroll
    for (int off = 32; off > 0; off >>= 1) {
        s1 += __shfl_xor(s1, off, 64);
        s2 += __shfl_xor(s2, off, 64);
    }
    int wave = tid >> 6, lane = tid & 63;
    if (lane == 0) { r1[wave] = s1; r2[wave] = s2; }
    __syncthreads();
    s1 = r1[0] + r1[1] + r1[2] + r1[3];
    s2 = r2[0] + r2[1] + r2[2] + r2[3];
    float mu = s1 / (float)C;
    float var = s2 / (float)C - mu * mu;
    float rstd = 1.0f / sqrtf(var + 1e-5f);
    #pragma unroll
    for (int t = 0; t < 6; ++t) {
        int c = tid + 256 * t;
        float y = (lv[t] - mu) * rstd * p.ln_g[c] + p.ln_b[c];
        p.oln[(size_t)b * C + c] = fmaxf(y, 0.f);
    }
}

// ---- final: reduce partH + fcn_b + relu + 4 head dots (blocks 0..31) ----
__device__ void final_stage(const Params& p, float* red) {
    int b = blockIdx.x, tid = threadIdx.x;
    float ph0 = 0.f, ph1 = 0.f, ph2 = 0.f, ptv = 0.f;
    #pragma unroll
    for (int t = 0; t < 12; ++t) {
        int j = tid + 256 * t;
        float s = 0.f;
        #pragma unroll
        for (int ss = 0; ss < 12; ++ss)
            s += p.partH[((size_t)ss * 32 + b) * D2 + j];
        s += p.fcn_b[j];
        s = fmaxf(s, 0.f);
        ptv += s * p.wt[j];
        int jj = tid + 256 * (t & 3);
        if (t < 4)       ph0 += s * p.w1[jj];
        else if (t < 8)  ph1 += s * p.w2[jj];
        else             ph2 += s * p.w3[jj];
    }
    #pragma unroll
    for (int off = 32; off > 0; off >>= 1) {
        ph0 += __shfl_xor(ph0, off, 64);
        ph1 += __shfl_xor(ph1, off, 64);
        ph2 += __shfl_xor(ph2, off, 64);
        ptv += __shfl_xor(ptv, off, 64);
    }
    int wave = tid >> 6, lane = tid & 63;
    if (lane == 0) {
        red[wave * 4 + 0] = ph0; red[wave * 4 + 1] = ph1;
        red[wave * 4 + 2] = ph2; red[wave * 4 + 3] = ptv;
    }
    __syncthreads();
    if (tid < 4) {
        float v = red[0 * 4 + tid] + red[1 * 4 + tid] + red[2 * 4 + tid] + red[3 * 4 + tid];
        float bias = (tid == 0) ? p.b1[0] : (tid == 1) ? p.b2[0] : (tid == 2) ? p.b3[0] : p.bt[0];
        p.out[b * 4 + tid] = v + bias;
    }
}

// ---- the persistent mega-kernel: 12 stages, 11 grid barriers, 1 launch ----
__global__ __launch_bounds__(NT, 2) void mega(Params p) {
    __shared__ float smem[6144];   // 24 KB: xs(2048) + wsm(4096); small stages overlay
    float* xs = smem;
    float* wsm = smem + 2048;
    int gid = blockIdx.x;

    // S1: theta partials = x @ theta_w.T (288 tiles)
    if (gid < 288) gemm_nn(p.x, p.theta_w, p.part, C, C, 2, gid / 12, gid % 12, xs, wsm);
    gridbar(p.bar, 0);
    // S2: theta = reduce + theta_b
    reduce12(p.part, p.theta_b, nullptr, p.theta);
    gridbar(p.bar, 1);
    // S3: u partials = theta @ phi_w (k-major W)
    if (gid < 288) gemm_nt(p.theta, p.phi_w, p.part, C, C, 2, gid / 12, gid % 12, xs, wsm);
    gridbar(p.bar, 2);
    // S4: u = reduce
    reduce12(p.part, nullptr, nullptr, p.u);
    gridbar(p.bar, 3);
    // S5: flash over lfb (all 512 blocks)
    flash_stage(p);
    gridbar(p.bar, 4);
    // S6: combine wave-partials -> vbuf
    if (gid < 192) combine_stage(p, smem);
    gridbar(p.bar, 5);
    // S7: o partials = vbuf @ gi_w.T
    if (gid < 288) gemm_nn(p.vbuf, p.gi_w, p.part, C, C, 2, gid / 12, gid % 12, xs, wsm);
    gridbar(p.bar, 6);
    // S8: oln = relu(LN(reduce + gi_b))
    if (gid < 32) ln_stage(p, smem, smem + 8);
    gridbar(p.bar, 7);
    // S9: o2 partials = oln @ fc_w.T
    if (gid < 288) gemm_nn(p.oln, p.fc_w, p.part, C, C, 2, gid / 12, gid % 12, xs, wsm);
    gridbar(p.bar, 8);
    // S10: lt = reduce + fc_b + x   (second half of feats)
    reduce12(p.part, p.fc_b, p.x, p.lt);
    gridbar(p.bar, 9);
    // S11: partH = [x | lt] @ fcn_w.T (576 tiles, grid-stride)
    for (int t = gid; t < 576; t += NB)
        gemm_feats(p.x, p.lt, p.fcn_w, p.partH, t / 12, t % 12, xs, wsm);
    gridbar(p.bar, 10);
    // S12: final heads
    if (gid < 32) final_stage(p, smem);
}

extern "C" void kernel_launch(void* const* d_in, const int* in_sizes, int n_in,
                              void* d_out, int out_size, void* d_ws, size_t ws_size,
                              hipStream_t stream) {
    (void)in_sizes; (void)n_in; (void)out_size; (void)ws_size;
    float* w = (float*)d_ws;

    Params p;
    p.x       = (const float*)d_in[0];
    p.lfb     = (const float*)d_in[1];
    p.theta_w = (const float*)d_in[2];
    p.theta_b = (const float*)d_in[3];
    p.phi_w   = (const float*)d_in[4];
    // d_in[5] = phi_b: additive per-row constant in softmax -> drops out
    p.gi_w    = (const float*)d_in[6];
    p.gi_b    = (const float*)d_in[7];
    p.ln_g    = (const float*)d_in[8];
    p.ln_b    = (const float*)d_in[9];
    p.fc_w    = (const float*)d_in[10];
    p.fc_b    = (const float*)d_in[11];
    p.fcn_w   = (const float*)d_in[12];
    p.fcn_b   = (const float*)d_in[13];
    p.w1 = (const float*)d_in[14]; p.b1 = (const float*)d_in[15];
    p.w2 = (const float*)d_in[16]; p.b2 = (const float*)d_in[17];
    p.w3 = (const float*)d_in[18]; p.b3 = (const float*)d_in[19];
    p.wt = (const float*)d_in[20]; p.bt = (const float*)d_in[21];
    p.out = (float*)d_out;

    // workspace layout (floats), all disjoint (~21 MB)
    p.part  = w;                   // 589824  (12 x 32 x C)
    p.partH = w + 589824;          // 1179648 (12 x 32 x D2)
    p.pv    = w + 1769472;         // 3145728 (32 x 64 x C)
    p.pm    = w + 4915200;         // 2048
    p.ps    = w + 4917248;         // 2048
    p.theta = w + 4919296;         // 49152
    p.u     = w + 4968448;         // 49152
    p.vbuf  = w + 5017600;         // 49152
    p.oln   = w + 5066752;         // 49152
    p.lt    = w + 5115904;         // 49152
    p.bar   = (unsigned*)(w + 5165056);  // 16 x u32

    // zero the single-use barrier counters (graph-capturable, 64 B)
    hipMemsetAsync((void*)p.bar, 0, 64, stream);

    mega<<<dim3(NB), dim3(NT), 0, stream>>>(p);
}

// Round 3
// 768.695 us; speedup vs baseline: 1.8965x; 1.8965x over previous
//
#include <hip/hip_runtime.h>
#include <math.h>

#define C 1536
#define D2 3072
#define L 1024
#define KC 64      // k-chunk per staging pass (16 float4 quads)
#define NB 512     // persistent grid: 2 blocks/CU on 256 CUs
#define NT 256
#define CH 16      // flash L-chunks: 16 chunks x 32 b = 512 blocks
#define LPW 16     // l's per wave = L/(CH*4)

__device__ inline float dot4(float4 a, float4 b) {
    return a.x * b.x + a.y * b.y + a.z * b.z + a.w * b.w;
}
__device__ inline float4 ld4(const float* p) { return *(const float4*)p; }
__device__ inline void   st4(float* p, float4 v) { *(float4*)p = v; }

// swizzled LDS quad address (float index): row*KC + (q ^ ((row>>2)&7))*4
__device__ inline int sw(int row, int q) {
    return row * KC + ((q ^ ((row >> 2) & 7)) << 2);
}

struct Params {
    const float *x, *lfb, *theta_w, *theta_b, *phi_w, *gi_w, *gi_b;
    const float *ln_g, *ln_b, *fc_w, *fc_b, *fcn_w, *fcn_b;
    const float *w1, *b1, *w2, *b2, *w3, *b3, *wt, *bt;
    float *out;
    float *part, *partH, *pv, *pm, *ps, *theta, *u, *vbuf, *oln, *lt;
    unsigned *bar;   // [0..15]=release counter line; [16 + 16*b]=per-block arrival flags
};

// ---- low-contention grid barrier (master/release, relaxed spins) ----
// Round-2 lesson: ACQUIRE spin-loads = per-poll L2 invalidate on every XCD ->
// write amplification (164MB) + 314 GB/s effective BW. Here: arrivals are
// relaxed stores to per-block 64B-strided flags (no RMW, no line contention);
// block 0 polls with relaxed loads and publishes a release phase; everyone
// does exactly ONE __threadfence (invalidate) on exit.
__device__ inline void gridbar(unsigned* bar, unsigned phase) {
    __syncthreads();                    // all block stage work done (vmcnt drained)
    unsigned* rel   = bar;
    unsigned* flags = bar + 16;
    int tid = threadIdx.x;
    if (blockIdx.x == 0) {
        if (tid == 0) __threadfence();  // release: writeback this XCD's L2
        __syncthreads();
        int b1 = tid + 1;               // 1..256
        int b2 = tid + 257;             // 257..511 (guarded)
        int rounds = 0, ok;
        do {
            unsigned f1 = __hip_atomic_load(flags + 16 * b1, __ATOMIC_RELAXED, __HIP_MEMORY_SCOPE_AGENT);
            unsigned f2 = (b2 < NB) ? __hip_atomic_load(flags + 16 * b2, __ATOMIC_RELAXED, __HIP_MEMORY_SCOPE_AGENT)
                                    : phase;
            ok = (f1 >= phase) & (f2 >= phase);
            if (!ok) __builtin_amdgcn_s_sleep(2);
        } while (!__syncthreads_and(ok) && ++rounds < (1 << 20));   // bail loud, not hang
        if (tid == 0) {
            __threadfence();            // acquire: invalidate stale L2 before consuming
            __hip_atomic_store(rel, phase, __ATOMIC_RELAXED, __HIP_MEMORY_SCOPE_AGENT);
        }
        __syncthreads();
    } else {
        if (tid == 0) {
            __threadfence();            // release this block's stage writes
            __hip_atomic_store(flags + 16 * blockIdx.x, phase, __ATOMIC_RELAXED, __HIP_MEMORY_SCOPE_AGENT);
            int spins = 0;
            while (__hip_atomic_load(rel, __ATOMIC_RELAXED, __HIP_MEMORY_SCOPE_AGENT) < phase) {
                __builtin_amdgcn_s_sleep(4);
                if (++spins > (1 << 22)) break;   // bail loud, not hang
            }
            __threadfence();            // acquire: single invalidate on exit
        }
        __syncthreads();
    }
}

// ---- split-K GEMM partial tile: A(32xK rm) @ W(NxK rm).T, one (jt,kb) tile ----
__device__ void gemm_nn(const float* __restrict__ A, const float* __restrict__ W,
                        float* __restrict__ part, int N, int K, int kchunks,
                        int jt, int kb, float* xs, float* wsm) {
    int tid = threadIdx.x;
    int j0 = jt * 64;
    int tb = tid & 15, tj = tid >> 4;
    float4 acc0 = make_float4(0.f, 0.f, 0.f, 0.f);
    float4 acc1 = make_float4(0.f, 0.f, 0.f, 0.f);
    for (int c = 0; c < kchunks; ++c) {
        int k0 = (kb * kchunks + c) * KC;
        __syncthreads();
        #pragma unroll
        for (int p = 0; p < 2; ++p) {
            int f = tid + 256 * p, row = f >> 4, q = f & 15;
            st4(xs + sw(row, q), ld4(A + (size_t)row * K + k0 + 4 * q));
        }
        #pragma unroll
        for (int p = 0; p < 4; ++p) {
            int f = tid + 256 * p, row = f >> 4, q = f & 15;
            st4(wsm + sw(row, q), ld4(W + (size_t)(j0 + row) * K + k0 + 4 * q));
        }
        __syncthreads();
        #pragma unroll
        for (int kq = 0; kq < 16; ++kq) {
            float4 x0 = ld4(xs + sw(2 * tb, kq));
            float4 x1 = ld4(xs + sw(2 * tb + 1, kq));
            float4 w0 = ld4(wsm + sw(4 * tj + 0, kq));
            float4 w1 = ld4(wsm + sw(4 * tj + 1, kq));
            float4 w2 = ld4(wsm + sw(4 * tj + 2, kq));
            float4 w3 = ld4(wsm + sw(4 * tj + 3, kq));
            acc0.x += dot4(x0, w0); acc0.y += dot4(x0, w1);
            acc0.z += dot4(x0, w2); acc0.w += dot4(x0, w3);
            acc1.x += dot4(x1, w0); acc1.y += dot4(x1, w1);
            acc1.z += dot4(x1, w2); acc1.w += dot4(x1, w3);
        }
    }
    st4(part + ((size_t)kb * 32 + 2 * tb + 0) * N + j0 + 4 * tj, acc0);
    st4(part + ((size_t)kb * 32 + 2 * tb + 1) * N + j0 + 4 * tj, acc1);
}

// ---- same, W stored k-major (KxN rm): transpose W tile through LDS ----
__device__ void gemm_nt(const float* __restrict__ A, const float* __restrict__ W,
                        float* __restrict__ part, int N, int K, int kchunks,
                        int jt, int kb, float* xs, float* wsm) {
    int tid = threadIdx.x;
    int j0 = jt * 64;
    int tb = tid & 15, tj = tid >> 4;
    float4 acc0 = make_float4(0.f, 0.f, 0.f, 0.f);
    float4 acc1 = make_float4(0.f, 0.f, 0.f, 0.f);
    for (int c = 0; c < kchunks; ++c) {
        int k0 = (kb * kchunks + c) * KC;
        __syncthreads();
        #pragma unroll
        for (int p = 0; p < 2; ++p) {
            int f = tid + 256 * p, row = f >> 4, q = f & 15;
            st4(xs + sw(row, q), ld4(A + (size_t)row * K + k0 + 4 * q));
        }
        #pragma unroll
        for (int p = 0; p < 4; ++p) {
            int f = tid + 256 * p;
            int r = f >> 4;          // k-row within tile
            int cq = f & 15;         // j-quad
            float4 v = ld4(W + (size_t)(k0 + r) * N + j0 + 4 * cq);
            wsm[sw(4 * cq + 0, r >> 2) + (r & 3)] = v.x;
            wsm[sw(4 * cq + 1, r >> 2) + (r & 3)] = v.y;
            wsm[sw(4 * cq + 2, r >> 2) + (r & 3)] = v.z;
            wsm[sw(4 * cq + 3, r >> 2) + (r & 3)] = v.w;
        }
        __syncthreads();
        #pragma unroll
        for (int kq = 0; kq < 16; ++kq) {
            float4 x0 = ld4(xs + sw(2 * tb, kq));
            float4 x1 = ld4(xs + sw(2 * tb + 1, kq));
            float4 w0 = ld4(wsm + sw(4 * tj + 0, kq));
            float4 w1 = ld4(wsm + sw(4 * tj + 1, kq));
            float4 w2 = ld4(wsm + sw(4 * tj + 2, kq));
            float4 w3 = ld4(wsm + sw(4 * tj + 3, kq));
            acc0.x += dot4(x0, w0); acc0.y += dot4(x0, w1);
            acc0.z += dot4(x0, w2); acc0.w += dot4(x0, w3);
            acc1.x += dot4(x1, w0); acc1.y += dot4(x1, w1);
            acc1.z += dot4(x1, w2); acc1.w += dot4(x1, w3);
        }
    }
    st4(part + ((size_t)kb * 32 + 2 * tb + 0) * N + j0 + 4 * tj, acc0);
    st4(part + ((size_t)kb * 32 + 2 * tb + 1) * N + j0 + 4 * tj, acc1);
}

// ---- fcn GEMM partial tile: A synthesized = [x | lt], W = D2 x D2 rm ----
__device__ void gemm_feats(const float* __restrict__ x, const float* __restrict__ lt,
                           const float* __restrict__ W, float* __restrict__ part,
                           int jt, int kb, float* xs, float* wsm) {
    int tid = threadIdx.x;
    int j0 = jt * 64;
    int tb = tid & 15, tj = tid >> 4;
    float4 acc0 = make_float4(0.f, 0.f, 0.f, 0.f);
    float4 acc1 = make_float4(0.f, 0.f, 0.f, 0.f);
    for (int c = 0; c < 4; ++c) {
        int k0 = (kb * 4 + c) * KC;
        __syncthreads();
        #pragma unroll
        for (int p = 0; p < 2; ++p) {
            int f = tid + 256 * p, row = f >> 4, q = f & 15;
            int kk = k0 + 4 * q;
            float4 v = (kk < C) ? ld4(x + (size_t)row * C + kk)
                                : ld4(lt + (size_t)row * C + kk - C);
            st4(xs + sw(row, q), v);
        }
        #pragma unroll
        for (int p = 0; p < 4; ++p) {
            int f = tid + 256 * p, row = f >> 4, q = f & 15;
            st4(wsm + sw(row, q), ld4(W + (size_t)(j0 + row) * D2 + k0 + 4 * q));
        }
        __syncthreads();
        #pragma unroll
        for (int kq = 0; kq < 16; ++kq) {
            float4 x0 = ld4(xs + sw(2 * tb, kq));
            float4 x1 = ld4(xs + sw(2 * tb + 1, kq));
            float4 w0 = ld4(wsm + sw(4 * tj + 0, kq));
            float4 w1 = ld4(wsm + sw(4 * tj + 1, kq));
            float4 w2 = ld4(wsm + sw(4 * tj + 2, kq));
            float4 w3 = ld4(wsm + sw(4 * tj + 3, kq));
            acc0.x += dot4(x0, w0); acc0.y += dot4(x0, w1);
            acc0.z += dot4(x0, w2); acc0.w += dot4(x0, w3);
            acc1.x += dot4(x1, w0); acc1.y += dot4(x1, w1);
            acc1.z += dot4(x1, w2); acc1.w += dot4(x1, w3);
        }
    }
    st4(part + ((size_t)kb * 32 + 2 * tb + 0) * D2 + j0 + 4 * tj, acc0);
    st4(part + ((size_t)kb * 32 + 2 * tb + 1) * D2 + j0 + 4 * tj, acc1);
}

// ---- elementwise 12-way split-K reduce (+bias, +addx) over 32 x C ----
__device__ inline void reduce12(const float* __restrict__ part, const float* __restrict__ bias,
                                const float* __restrict__ addx, float* __restrict__ outp) {
    int i = blockIdx.x * NT + threadIdx.x;
    if (i < 32 * C) {
        int b = i / C, j = i - b * C;
        float s = 0.f;
        #pragma unroll
        for (int kk = 0; kk < 12; ++kk) s += part[((size_t)kk * 32 + b) * C + j];
        if (bias) s += bias[j];
        if (addx) s += addx[i];
        outp[i] = s;
    }
}

// ---- flash stage: scores + online softmax + weighted lfb accumulation ----
__device__ void flash_stage(const Params& p) {
    int gid = blockIdx.x;
    int b = gid & 31, chunk = gid >> 5;
    int wave = threadIdx.x >> 6, lane = threadIdx.x & 63;
    int widx = chunk * 4 + wave;

    const float scale = 39.19183588453085f;  // sqrt(1536)

    float uu[24];
    const float* ub = p.u + (size_t)b * C;
    #pragma unroll
    for (int t = 0; t < 6; ++t)
        *(float4*)(uu + 4 * t) = ld4(ub + 4 * lane + 256 * t);

    float m = -INFINITY, s = 0.f;
    float vv[24];
    #pragma unroll
    for (int t = 0; t < 24; ++t) vv[t] = 0.f;

    int l0 = chunk * (L / CH) + wave;
    for (int i = 0; i < LPW; ++i) {
        int l = l0 + i * 4;
        const float* row = p.lfb + ((size_t)b * L + l) * C;
        float xx[24];
        #pragma unroll
        for (int t = 0; t < 6; ++t)
            *(float4*)(xx + 4 * t) = ld4(row + 4 * lane + 256 * t);
        float d = 0.f;
        #pragma unroll
        for (int t = 0; t < 24; ++t) d += xx[t] * uu[t];
        #pragma unroll
        for (int off = 32; off > 0; off >>= 1) d += __shfl_xor(d, off, 64);
        float score = d * scale;
        float mn = fmaxf(m, score);
        float alpha = __expf(m - mn);
        float pr = __expf(score - mn);
        s = s * alpha + pr;
        #pragma unroll
        for (int t = 0; t < 24; ++t) vv[t] = vv[t] * alpha + pr * xx[t];
        m = mn;
    }

    if (lane == 0) { p.pm[b * 64 + widx] = m; p.ps[b * 64 + widx] = s; }
    float* pvb = p.pv + ((size_t)b * 64 + widx) * C;
    #pragma unroll
    for (int t = 0; t < 6; ++t)
        st4(pvb + 4 * lane + 256 * t, *(float4*)(vv + 4 * t));
}

// ---- combine wave-partials -> vbuf[b][c] (blocks 0..191) ----
__device__ void combine_stage(const Params& p, float* coef) {
    int gid = blockIdx.x;
    int b = gid & 31, cc = gid >> 5;
    int tid = threadIdx.x;
    if (tid < 64) {
        float mj = p.pm[b * 64 + tid];
        float M = mj;
        #pragma unroll
        for (int off = 32; off > 0; off >>= 1) M = fmaxf(M, __shfl_xor(M, off, 64));
        float ej = expf(mj - M);
        float S = p.ps[b * 64 + tid] * ej;
        #pragma unroll
        for (int off = 32; off > 0; off >>= 1) S += __shfl_xor(S, off, 64);
        coef[tid] = ej / S;
    }
    __syncthreads();
    int c = cc * 256 + tid;
    float acc = 0.f;
    #pragma unroll 8
    for (int j = 0; j < 64; ++j)
        acc += coef[j] * p.pv[((size_t)b * 64 + j) * C + c];
    p.vbuf[(size_t)b * C + c] = acc;
}

// ---- split-K reduce + gi_b + layernorm + relu (blocks 0..31) ----
__device__ void ln_stage(const Params& p, float* r1, float* r2) {
    int b = blockIdx.x, tid = threadIdx.x;
    float lv[6];
    float s1 = 0.f, s2 = 0.f;
    #pragma unroll
    for (int t = 0; t < 6; ++t) {
        int c = tid + 256 * t;
        float acc = 0.f;
        #pragma unroll
        for (int kk = 0; kk < 12; ++kk) acc += p.part[((size_t)kk * 32 + b) * C + c];
        acc += p.gi_b[c];
        lv[t] = acc; s1 += acc; s2 += acc * acc;
    }
    #pragma unroll
    for (int off = 32; off > 0; off >>= 1) {
        s1 += __shfl_xor(s1, off, 64);
        s2 += __shfl_xor(s2, off, 64);
    }
    int wave = tid >> 6, lane = tid & 63;
    if (lane == 0) { r1[wave] = s1; r2[wave] = s2; }
    __syncthreads();
    s1 = r1[0] + r1[1] + r1[2] + r1[3];
    s2 = r2[0] + r2[1] + r2[2] + r2[3];
    float mu = s1 / (float)C;
    float var = s2 / (float)C - mu * mu;
    float rstd = 1.0f / sqrtf(var + 1e-5f);
    #pragma unroll
    for (int t = 0; t < 6; ++t) {
        int c = tid + 256 * t;
        float y = (lv[t] - mu) * rstd * p.ln_g[c] + p.ln_b[c];
        p.oln[(size_t)b * C + c] = fmaxf(y, 0.f);
    }
}

// ---- final: reduce partH + fcn_b + relu + 4 head dots (blocks 0..31) ----
__device__ void final_stage(const Params& p, float* red) {
    int b = blockIdx.x, tid = threadIdx.x;
    float ph0 = 0.f, ph1 = 0.f, ph2 = 0.f, ptv = 0.f;
    #pragma unroll
    for (int t = 0; t < 12; ++t) {
        int j = tid + 256 * t;
        float s = 0.f;
        #pragma unroll
        for (int ss = 0; ss < 12; ++ss)
            s += p.partH[((size_t)ss * 32 + b) * D2 + j];
        s += p.fcn_b[j];
        s = fmaxf(s, 0.f);
        ptv += s * p.wt[j];
        int jj = tid + 256 * (t & 3);
        if (t < 4)       ph0 += s * p.w1[jj];
        else if (t < 8)  ph1 += s * p.w2[jj];
        else             ph2 += s * p.w3[jj];
    }
    #pragma unroll
    for (int off = 32; off > 0; off >>= 1) {
        ph0 += __shfl_xor(ph0, off, 64);
        ph1 += __shfl_xor(ph1, off, 64);
        ph2 += __shfl_xor(ph2, off, 64);
        ptv += __shfl_xor(ptv, off, 64);
    }
    int wave = tid >> 6, lane = tid & 63;
    if (lane == 0) {
        red[wave * 4 + 0] = ph0; red[wave * 4 + 1] = ph1;
        red[wave * 4 + 2] = ph2; red[wave * 4 + 3] = ptv;
    }
    __syncthreads();
    if (tid < 4) {
        float v = red[0 * 4 + tid] + red[1 * 4 + tid] + red[2 * 4 + tid] + red[3 * 4 + tid];
        float bias = (tid == 0) ? p.b1[0] : (tid == 1) ? p.b2[0] : (tid == 2) ? p.b3[0] : p.bt[0];
        p.out[b * 4 + tid] = v + bias;
    }
}

// ---- the persistent mega-kernel: 12 stages, 11 grid barriers, 1 launch ----
__global__ __launch_bounds__(NT, 2) void mega(Params p) {
    __shared__ float smem[6144];   // 24 KB: xs(2048) + wsm(4096); small stages overlay
    float* xs = smem;
    float* wsm = smem + 2048;
    int gid = blockIdx.x;

    // S1: theta partials = x @ theta_w.T (288 tiles)
    if (gid < 288) gemm_nn(p.x, p.theta_w, p.part, C, C, 2, gid / 12, gid % 12, xs, wsm);
    gridbar(p.bar, 1);
    // S2: theta = reduce + theta_b
    reduce12(p.part, p.theta_b, nullptr, p.theta);
    gridbar(p.bar, 2);
    // S3: u partials = theta @ phi_w (k-major W)
    if (gid < 288) gemm_nt(p.theta, p.phi_w, p.part, C, C, 2, gid / 12, gid % 12, xs, wsm);
    gridbar(p.bar, 3);
    // S4: u = reduce
    reduce12(p.part, nullptr, nullptr, p.u);
    gridbar(p.bar, 4);
    // S5: flash over lfb (all 512 blocks)
    flash_stage(p);
    gridbar(p.bar, 5);
    // S6: combine wave-partials -> vbuf
    if (gid < 192) combine_stage(p, smem);
    gridbar(p.bar, 6);
    // S7: o partials = vbuf @ gi_w.T
    if (gid < 288) gemm_nn(p.vbuf, p.gi_w, p.part, C, C, 2, gid / 12, gid % 12, xs, wsm);
    gridbar(p.bar, 7);
    // S8: oln = relu(LN(reduce + gi_b))
    if (gid < 32) ln_stage(p, smem, smem + 8);
    gridbar(p.bar, 8);
    // S9: o2 partials = oln @ fc_w.T
    if (gid < 288) gemm_nn(p.oln, p.fc_w, p.part, C, C, 2, gid / 12, gid % 12, xs, wsm);
    gridbar(p.bar, 9);
    // S10: lt = reduce + fc_b + x   (second half of feats)
    reduce12(p.part, p.fc_b, p.x, p.lt);
    gridbar(p.bar, 10);
    // S11: partH = [x | lt] @ fcn_w.T (576 tiles, grid-stride)
    for (int t = gid; t < 576; t += NB)
        gemm_feats(p.x, p.lt, p.fcn_w, p.partH, t / 12, t % 12, xs, wsm);
    gridbar(p.bar, 11);
    // S12: final heads
    if (gid < 32) final_stage(p, smem);
}

extern "C" void kernel_launch(void* const* d_in, const int* in_sizes, int n_in,
                              void* d_out, int out_size, void* d_ws, size_t ws_size,
                              hipStream_t stream) {
    (void)in_sizes; (void)n_in; (void)out_size; (void)ws_size;
    float* w = (float*)d_ws;

    Params p;
    p.x       = (const float*)d_in[0];
    p.lfb     = (const float*)d_in[1];
    p.theta_w = (const float*)d_in[2];
    p.theta_b = (const float*)d_in[3];
    p.phi_w   = (const float*)d_in[4];
    // d_in[5] = phi_b: additive per-row constant in softmax -> drops out
    p.gi_w    = (const float*)d_in[6];
    p.gi_b    = (const float*)d_in[7];
    p.ln_g    = (const float*)d_in[8];
    p.ln_b    = (const float*)d_in[9];
    p.fc_w    = (const float*)d_in[10];
    p.fc_b    = (const float*)d_in[11];
    p.fcn_w   = (const float*)d_in[12];
    p.fcn_b   = (const float*)d_in[13];
    p.w1 = (const float*)d_in[14]; p.b1 = (const float*)d_in[15];
    p.w2 = (const float*)d_in[16]; p.b2 = (const float*)d_in[17];
    p.w3 = (const float*)d_in[18]; p.b3 = (const float*)d_in[19];
    p.wt = (const float*)d_in[20]; p.bt = (const float*)d_in[21];
    p.out = (float*)d_out;

    // workspace layout (floats), all disjoint (~21 MB)
    p.part  = w;                   // 589824  (12 x 32 x C)
    p.partH = w + 589824;          // 1179648 (12 x 32 x D2)
    p.pv    = w + 1769472;         // 3145728 (32 x 64 x C)
    p.pm    = w + 4915200;         // 2048
    p.ps    = w + 4917248;         // 2048
    p.theta = w + 4919296;         // 49152
    p.u     = w + 4968448;         // 49152
    p.vbuf  = w + 5017600;         // 49152
    p.oln   = w + 5066752;         // 49152
    p.lt    = w + 5115904;         // 49152
    p.bar   = (unsigned*)(w + 5165056);  // rel(16 u32) + flags(512*16 u32)

    // zero the barrier region: 16 + 512*16 u32 = 32832 B (graph-capturable)
    hipMemsetAsync((void*)p.bar, 0, (16 + NB * 16) * sizeof(unsigned), stream);

    mega<<<dim3(NB), dim3(NT), 0, stream>>>(p);
}

// Round 4
// 488.698 us; speedup vs baseline: 2.9831x; 1.5729x over previous
//
#include <hip/hip_runtime.h>
#include <math.h>

#define B 32
#define C 1536
#define D2 3072
#define L 1024
#define KC 64      // k-chunk per staging pass (16 float4 quads)
#define CH 16      // flash L-chunks -> grid 16x32, 64 wave-partials per b
#define LPW 16     // l's per wave = L/(CH*4)

__device__ inline float dot4(float4 a, float4 b) {
    return a.x * b.x + a.y * b.y + a.z * b.z + a.w * b.w;
}
__device__ inline float4 ld4(const float* p) { return *(const float4*)p; }
__device__ inline void   st4(float* p, float4 v) { *(float4*)p = v; }

// swizzled LDS quad address (float index): row*KC + (q ^ ((row>>2)&7))*4
__device__ inline int sw(int row, int q) {
    return row * KC + ((q ^ ((row >> 2) & 7)) << 2);
}

// sum the 12 split-K slices of part at (row, col..col+3); order kk=0..11
// matches the round-0 reduce kernels bit-exactly (0+x == x in fp32).
__device__ inline float4 sum12(const float* __restrict__ part, int row, int col, int N) {
    float4 s = ld4(part + (size_t)row * N + col);
    #pragma unroll
    for (int kk = 1; kk < 12; ++kk) {
        float4 t = ld4(part + ((size_t)kk * 32 + row) * N + col);
        s.x += t.x; s.y += t.y; s.z += t.z; s.w += t.w;
    }
    return s;
}

// ---------------- split-K GEMM: 32b x 64j tile, 2x4/thread, 12 kb slices ----------------
// part[(kb*32+b)*N + j] = sum over this block's K-slice of A[b,k]*W[j,k]
__global__ __launch_bounds__(256) void gemm32(const float* __restrict__ A,   // 32 x K
                                              const float* __restrict__ W,   // N x K
                                              float* __restrict__ part,
                                              int N, int K, int kchunks) {
    __shared__ float xs[32 * KC];    // 8 KB
    __shared__ float wsm[64 * KC];   // 16 KB
    int tid = threadIdx.x;
    int j0 = blockIdx.x * 64;
    int kb = blockIdx.y;
    int tb = tid & 15;       // 16 b-groups of 2 rows
    int tj = tid >> 4;       // 16 j-groups of 4 cols

    float4 acc0 = make_float4(0.f, 0.f, 0.f, 0.f);
    float4 acc1 = make_float4(0.f, 0.f, 0.f, 0.f);

    for (int c = 0; c < kchunks; ++c) {
        int k0 = (kb * kchunks + c) * KC;
        __syncthreads();
        #pragma unroll
        for (int p = 0; p < 2; ++p) {
            int f = tid + 256 * p;
            int row = f >> 4, q = f & 15;
            st4(xs + sw(row, q), ld4(A + (size_t)row * K + k0 + 4 * q));
        }
        #pragma unroll
        for (int p = 0; p < 4; ++p) {
            int f = tid + 256 * p;
            int row = f >> 4, q = f & 15;
            st4(wsm + sw(row, q), ld4(W + (size_t)(j0 + row) * K + k0 + 4 * q));
        }
        __syncthreads();
        #pragma unroll
        for (int kq = 0; kq < 16; ++kq) {
            float4 x0 = ld4(xs + sw(2 * tb, kq));
            float4 x1 = ld4(xs + sw(2 * tb + 1, kq));
            float4 w0 = ld4(wsm + sw(4 * tj + 0, kq));
            float4 w1 = ld4(wsm + sw(4 * tj + 1, kq));
            float4 w2 = ld4(wsm + sw(4 * tj + 2, kq));
            float4 w3 = ld4(wsm + sw(4 * tj + 3, kq));
            acc0.x += dot4(x0, w0); acc0.y += dot4(x0, w1);
            acc0.z += dot4(x0, w2); acc0.w += dot4(x0, w3);
            acc1.x += dot4(x1, w0); acc1.y += dot4(x1, w1);
            acc1.z += dot4(x1, w2); acc1.w += dot4(x1, w3);
        }
    }
    st4(part + ((size_t)kb * 32 + 2 * tb + 0) * N + j0 + 4 * tj, acc0);
    st4(part + ((size_t)kb * 32 + 2 * tb + 1) * N + j0 + 4 * tj, acc1);
}

// ---------------- u-GEMM: A = reduce12(partT)+theta_b on the fly; W k-major ----------------
// partU[(kb*32+b)*C + j] = slice of theta @ phi_w. Kills the theta-reduce launch
// and the transpose launch (W tile transposed through LDS during staging).
__global__ __launch_bounds__(256) void gemm_u(const float* __restrict__ pT,   // 12 x 32 x C
                                              const float* __restrict__ tb_,  // theta_b
                                              const float* __restrict__ W,    // C x C, k-major
                                              float* __restrict__ part) {
    __shared__ float xs[32 * KC];
    __shared__ float wsm[64 * KC];
    int tid = threadIdx.x;
    int j0 = blockIdx.x * 64;
    int kb = blockIdx.y;
    int tb = tid & 15, tj = tid >> 4;

    float4 acc0 = make_float4(0.f, 0.f, 0.f, 0.f);
    float4 acc1 = make_float4(0.f, 0.f, 0.f, 0.f);

    for (int c = 0; c < 2; ++c) {
        int k0 = (kb * 2 + c) * KC;
        __syncthreads();
        #pragma unroll
        for (int p = 0; p < 2; ++p) {
            int f = tid + 256 * p;
            int row = f >> 4, q = f & 15;
            int col = k0 + 4 * q;
            float4 v = sum12(pT, row, col, C);        // theta = sum slices...
            float4 b4 = ld4(tb_ + col);               // ...then + theta_b (round-0 order)
            v.x += b4.x; v.y += b4.y; v.z += b4.z; v.w += b4.w;
            st4(xs + sw(row, q), v);
        }
        // W tile: 64 k-rows x 64 j-cols, coalesced along j, scatter to wsm[j][k]
        #pragma unroll
        for (int p = 0; p < 4; ++p) {
            int f = tid + 256 * p;
            int r = f >> 4;          // k-row within tile
            int cq = f & 15;         // j-quad
            float4 v = ld4(W + (size_t)(k0 + r) * C + j0 + 4 * cq);
            wsm[sw(4 * cq + 0, r >> 2) + (r & 3)] = v.x;
            wsm[sw(4 * cq + 1, r >> 2) + (r & 3)] = v.y;
            wsm[sw(4 * cq + 2, r >> 2) + (r & 3)] = v.z;
            wsm[sw(4 * cq + 3, r >> 2) + (r & 3)] = v.w;
        }
        __syncthreads();
        #pragma unroll
        for (int kq = 0; kq < 16; ++kq) {
            float4 x0 = ld4(xs + sw(2 * tb, kq));
            float4 x1 = ld4(xs + sw(2 * tb + 1, kq));
            float4 w0 = ld4(wsm + sw(4 * tj + 0, kq));
            float4 w1 = ld4(wsm + sw(4 * tj + 1, kq));
            float4 w2 = ld4(wsm + sw(4 * tj + 2, kq));
            float4 w3 = ld4(wsm + sw(4 * tj + 3, kq));
            acc0.x += dot4(x0, w0); acc0.y += dot4(x0, w1);
            acc0.z += dot4(x0, w2); acc0.w += dot4(x0, w3);
            acc1.x += dot4(x1, w0); acc1.y += dot4(x1, w1);
            acc1.z += dot4(x1, w2); acc1.w += dot4(x1, w3);
        }
    }
    st4(part + ((size_t)kb * 32 + 2 * tb + 0) * C + j0 + 4 * tj, acc0);
    st4(part + ((size_t)kb * 32 + 2 * tb + 1) * C + j0 + 4 * tj, acc1);
}

// ---------------- h-GEMM: A = [x | x + reduce12(partF)+fc_b] on the fly ----------------
__global__ __launch_bounds__(256) void gemm_h(const float* __restrict__ x,
                                              const float* __restrict__ pF,   // 12 x 32 x C
                                              const float* __restrict__ fcb,
                                              const float* __restrict__ W,    // D2 x D2
                                              float* __restrict__ part) {
    __shared__ float xs[32 * KC];
    __shared__ float wsm[64 * KC];
    int tid = threadIdx.x;
    int j0 = blockIdx.x * 64;
    int kb = blockIdx.y;
    int tb = tid & 15, tj = tid >> 4;

    float4 acc0 = make_float4(0.f, 0.f, 0.f, 0.f);
    float4 acc1 = make_float4(0.f, 0.f, 0.f, 0.f);

    for (int c = 0; c < 4; ++c) {
        int k0 = (kb * 4 + c) * KC;
        __syncthreads();
        #pragma unroll
        for (int p = 0; p < 2; ++p) {
            int f = tid + 256 * p;
            int row = f >> 4, q = f & 15;
            int kk = k0 + 4 * q;
            float4 v;
            if (kk < C) {
                v = ld4(x + (size_t)row * C + kk);
            } else {
                int col = kk - C;
                float4 s = sum12(pF, row, col, C);    // o2 = sum slices
                float4 b4 = ld4(fcb + col);           // + fc_b
                float4 xa = ld4(x + (size_t)row * C + col);
                v.x = (s.x + b4.x) + xa.x;            // lt = (sum + bias) + x  (round-0 order)
                v.y = (s.y + b4.y) + xa.y;
                v.z = (s.z + b4.z) + xa.z;
                v.w = (s.w + b4.w) + xa.w;
            }
            st4(xs + sw(row, q), v);
        }
        #pragma unroll
        for (int p = 0; p < 4; ++p) {
            int f = tid + 256 * p;
            int row = f >> 4, q = f & 15;
            st4(wsm + sw(row, q), ld4(W + (size_t)(j0 + row) * D2 + k0 + 4 * q));
        }
        __syncthreads();
        #pragma unroll
        for (int kq = 0; kq < 16; ++kq) {
            float4 x0 = ld4(xs + sw(2 * tb, kq));
            float4 x1 = ld4(xs + sw(2 * tb + 1, kq));
            float4 w0 = ld4(wsm + sw(4 * tj + 0, kq));
            float4 w1 = ld4(wsm + sw(4 * tj + 1, kq));
            float4 w2 = ld4(wsm + sw(4 * tj + 2, kq));
            float4 w3 = ld4(wsm + sw(4 * tj + 3, kq));
            acc0.x += dot4(x0, w0); acc0.y += dot4(x0, w1);
            acc0.z += dot4(x0, w2); acc0.w += dot4(x0, w3);
            acc1.x += dot4(x1, w0); acc1.y += dot4(x1, w1);
            acc1.z += dot4(x1, w2); acc1.w += dot4(x1, w3);
        }
    }
    st4(part + ((size_t)kb * 32 + 2 * tb + 0) * D2 + j0 + 4 * tj, acc0);
    st4(part + ((size_t)kb * 32 + 2 * tb + 1) * D2 + j0 + 4 * tj, acc1);
}

// ---------------- split-K reduce + bias + layernorm + relu (32 rows) ----------------
__global__ __launch_bounds__(256) void reduce_ln_relu(const float* __restrict__ part,
                                                      const float* __restrict__ bias,
                                                      const float* __restrict__ g,
                                                      const float* __restrict__ bt,
                                                      float* __restrict__ out) {
    int b = blockIdx.x, tid = threadIdx.x;
    __shared__ float r1[4], r2[4];
    float lv[6];
    float s1 = 0.f, s2 = 0.f;
    #pragma unroll
    for (int t = 0; t < 6; ++t) {
        int c = tid + 256 * t;
        float acc = 0.f;
        #pragma unroll
        for (int kk = 0; kk < 12; ++kk) acc += part[((size_t)kk * 32 + b) * C + c];
        acc += bias[c];
        lv[t] = acc; s1 += acc; s2 += acc * acc;
    }
    #pragma unroll
    for (int off = 32; off > 0; off >>= 1) {
        s1 += __shfl_xor(s1, off, 64);
        s2 += __shfl_xor(s2, off, 64);
    }
    int wave = tid >> 6, lane = tid & 63;
    if (lane == 0) { r1[wave] = s1; r2[wave] = s2; }
    __syncthreads();
    s1 = r1[0] + r1[1] + r1[2] + r1[3];
    s2 = r2[0] + r2[1] + r2[2] + r2[3];
    float mu = s1 / (float)C;
    float var = s2 / (float)C - mu * mu;
    float rstd = 1.0f / sqrtf(var + 1e-5f);
    #pragma unroll
    for (int t = 0; t < 6; ++t) {
        int c = tid + 256 * t;
        float y = (lv[t] - mu) * rstd * g[c] + bt[c];
        out[(size_t)b * C + c] = fmaxf(y, 0.f);
    }
}

// ---------------- flash: u reduced into LDS, then scores + online softmax ----------------
__global__ __launch_bounds__(256) void flash_k(const float* __restrict__ pU,   // 12 x 32 x C
                                               const float* __restrict__ lfb,  // 32 x L x C
                                               float* __restrict__ pm,
                                               float* __restrict__ ps,
                                               float* __restrict__ pv) {
    __shared__ float u_lds[C];       // 6 KB
    int chunk = blockIdx.x;          // 0..CH-1
    int b = blockIdx.y;              // 0..31
    int tid = threadIdx.x;
    int wave = tid >> 6;             // 0..3
    int lane = tid & 63;
    int widx = chunk * 4 + wave;     // 0..63

    const float scale = 39.19183588453085f;  // sqrt(1536)

    // u-row = reduce12(partU) (no bias), built once per block in LDS
    #pragma unroll
    for (int t = 0; t < 6; ++t) {
        int cc = tid + 256 * t;
        float s = 0.f;
        #pragma unroll
        for (int kk = 0; kk < 12; ++kk) s += pU[((size_t)kk * 32 + b) * C + cc];
        u_lds[cc] = s;
    }
    __syncthreads();

    float uu[24];
    #pragma unroll
    for (int t = 0; t < 6; ++t)
        *(float4*)(uu + 4 * t) = ld4(u_lds + 4 * lane + 256 * t);

    float m = -INFINITY, s = 0.f;
    float vv[24];
    #pragma unroll
    for (int t = 0; t < 24; ++t) vv[t] = 0.f;

    int l0 = chunk * (L / CH) + wave;        // stride 4 within chunk
    for (int i = 0; i < LPW; ++i) {
        int l = l0 + i * 4;
        const float* row = lfb + ((size_t)b * L + l) * C;
        float xx[24];
        #pragma unroll
        for (int t = 0; t < 6; ++t)
            *(float4*)(xx + 4 * t) = ld4(row + 4 * lane + 256 * t);
        float d = 0.f;
        #pragma unroll
        for (int t = 0; t < 24; ++t) d += xx[t] * uu[t];
        #pragma unroll
        for (int off = 32; off > 0; off >>= 1) d += __shfl_xor(d, off, 64);
        float score = d * scale;
        float mn = fmaxf(m, score);
        float alpha = __expf(m - mn);        // 0 when m == -inf
        float p = __expf(score - mn);
        s = s * alpha + p;
        #pragma unroll
        for (int t = 0; t < 24; ++t) vv[t] = vv[t] * alpha + p * xx[t];
        m = mn;
    }

    if (lane == 0) { pm[b * 64 + widx] = m; ps[b * 64 + widx] = s; }
    float* pvb = pv + ((size_t)b * 64 + widx) * C;
    #pragma unroll
    for (int t = 0; t < 6; ++t)
        st4(pvb + 4 * lane + 256 * t, *(float4*)(vv + 4 * t));
}

// ---------------- combine wave-partials -> v[b][c] ----------------
__global__ __launch_bounds__(256) void combine_k(const float* __restrict__ pm,
                                                 const float* __restrict__ ps,
                                                 const float* __restrict__ pv,
                                                 float* __restrict__ v) {
    int cc = blockIdx.x;             // 0..5
    int b = blockIdx.y;              // 0..31
    int tid = threadIdx.x;
    __shared__ float coef[64];
    if (tid < 64) {
        float mj = pm[b * 64 + tid];
        float M = mj;
        #pragma unroll
        for (int off = 32; off > 0; off >>= 1) M = fmaxf(M, __shfl_xor(M, off, 64));
        float ej = expf(mj - M);
        float S = ps[b * 64 + tid] * ej;
        #pragma unroll
        for (int off = 32; off > 0; off >>= 1) S += __shfl_xor(S, off, 64);
        coef[tid] = ej / S;
    }
    __syncthreads();
    int c = cc * 256 + tid;
    float acc = 0.f;
    #pragma unroll 8
    for (int j = 0; j < 64; ++j)
        acc += coef[j] * pv[((size_t)b * 64 + j) * C + c];
    v[(size_t)b * C + c] = acc;
}

// ---------------- final: reduce fcn partials + bias + relu + 4 head dots ----------------
__global__ __launch_bounds__(256) void final_k(const float* __restrict__ partH, // 12 x 32 x D2
                                               const float* __restrict__ fcn_b,
                                               const float* __restrict__ w1, const float* __restrict__ b1,
                                               const float* __restrict__ w2, const float* __restrict__ b2,
                                               const float* __restrict__ w3, const float* __restrict__ b3,
                                               const float* __restrict__ wt, const float* __restrict__ bt,
                                               float* __restrict__ out) {
    int b = blockIdx.x;
    int tid = threadIdx.x;
    float ph0 = 0.f, ph1 = 0.f, ph2 = 0.f, ptv = 0.f;
    #pragma unroll
    for (int t = 0; t < 12; ++t) {
        int j = tid + 256 * t;
        float s = 0.f;
        #pragma unroll
        for (int ss = 0; ss < 12; ++ss)
            s += partH[((size_t)ss * 32 + b) * D2 + j];
        s += fcn_b[j];
        s = fmaxf(s, 0.f);
        ptv += s * wt[j];
        int jj = tid + 256 * (t & 3);
        if (t < 4)       ph0 += s * w1[jj];
        else if (t < 8)  ph1 += s * w2[jj];
        else             ph2 += s * w3[jj];
    }
    #pragma unroll
    for (int off = 32; off > 0; off >>= 1) {
        ph0 += __shfl_xor(ph0, off, 64);
        ph1 += __shfl_xor(ph1, off, 64);
        ph2 += __shfl_xor(ph2, off, 64);
        ptv += __shfl_xor(ptv, off, 64);
    }
    __shared__ float red[4][4];
    int wave = tid >> 6, lane = tid & 63;
    if (lane == 0) {
        red[wave][0] = ph0; red[wave][1] = ph1; red[wave][2] = ph2; red[wave][3] = ptv;
    }
    __syncthreads();
    if (tid < 4) {
        float v = red[0][tid] + red[1][tid] + red[2][tid] + red[3][tid];
        float bias = (tid == 0) ? b1[0] : (tid == 1) ? b2[0] : (tid == 2) ? b3[0] : bt[0];
        out[b * 4 + tid] = v + bias;
    }
}

extern "C" void kernel_launch(void* const* d_in, const int* in_sizes, int n_in,
                              void* d_out, int out_size, void* d_ws, size_t ws_size,
                              hipStream_t stream) {
    (void)in_sizes; (void)n_in; (void)out_size; (void)ws_size;
    const float* x       = (const float*)d_in[0];
    const float* lfb     = (const float*)d_in[1];
    const float* theta_w = (const float*)d_in[2];
    const float* theta_b = (const float*)d_in[3];
    const float* phi_w   = (const float*)d_in[4];
    // d_in[5] = phi_b: additive per-row constant in softmax -> drops out
    const float* gi_w    = (const float*)d_in[6];
    const float* gi_b    = (const float*)d_in[7];
    const float* ln_g    = (const float*)d_in[8];
    const float* ln_b    = (const float*)d_in[9];
    const float* fc_w    = (const float*)d_in[10];
    const float* fc_b    = (const float*)d_in[11];
    const float* fcn_w   = (const float*)d_in[12];
    const float* fcn_b   = (const float*)d_in[13];
    const float* w1 = (const float*)d_in[14]; const float* b1 = (const float*)d_in[15];
    const float* w2 = (const float*)d_in[16]; const float* b2 = (const float*)d_in[17];
    const float* w3 = (const float*)d_in[18]; const float* b3 = (const float*)d_in[19];
    const float* wt = (const float*)d_in[20]; const float* bt = (const float*)d_in[21];
    float* out = (float*)d_out;
    float* w = (float*)d_ws;

    // workspace layout (floats), all disjoint (~27 MB)
    float* partT = w;                  // 589824  (12 x 32 x C)
    float* partU = w + 589824;         // 589824
    float* partG = w + 1179648;        // 589824
    float* partF = w + 1769472;        // 589824
    float* partH = w + 2359296;        // 1179648 (12 x 32 x D2)
    float* pv    = w + 3538944;        // 3145728 (32 x 64 x C)
    float* pm    = w + 6684672;        // 2048
    float* ps    = w + 6686720;        // 2048
    float* vbuf  = w + 6688768;        // 49152
    float* oln   = w + 6737920;        // 49152

    // 1: theta slices = x @ theta_w.T
    gemm32<<<dim3(24, 12), 256, 0, stream>>>(x, theta_w, partT, C, C, 2);

    // 2: u slices = (reduce12(partT)+theta_b) @ phi_w   (reduce + transpose fused)
    gemm_u<<<dim3(24, 12), 256, 0, stream>>>(partT, theta_b, phi_w, partU);

    // 3: flash over lfb (u reduced in-kernel via LDS)
    flash_k<<<dim3(CH, B), 256, 0, stream>>>(partU, lfb, pm, ps, pv);

    // 4: combine wave-partials -> vbuf
    combine_k<<<dim3(6, B), 256, 0, stream>>>(pm, ps, pv, vbuf);

    // 5: o slices = vbuf @ gi_w.T
    gemm32<<<dim3(24, 12), 256, 0, stream>>>(vbuf, gi_w, partG, C, C, 2);

    // 6: oln = relu(LN(reduce12(partG) + gi_b))
    reduce_ln_relu<<<B, 256, 0, stream>>>(partG, gi_b, ln_g, ln_b, oln);

    // 7: o2 slices = oln @ fc_w.T
    gemm32<<<dim3(24, 12), 256, 0, stream>>>(oln, fc_w, partF, C, C, 2);

    // 8: partH slices = [x | x + reduce12(partF)+fc_b] @ fcn_w.T  (reduce fused)
    gemm_h<<<dim3(48, 12), 256, 0, stream>>>(x, partF, fc_b, fcn_w, partH);

    // 9: reduce + bias + relu + 4 head dots
    final_k<<<B, 256, 0, stream>>>(partH, fcn_b, w1, b1, w2, b2, w3, b3, wt, bt, out);
}